// Round 6
// baseline (161.740 us; speedup 1.0000x reference)
//
#include <hip/hip_runtime.h>
#include <hip/hip_fp16.h>

#define NN 100000
#define NE 1000000
#define FIN 64
#define FHID 32
#define DEGB ((NE + 255) / 256)   // 3907
#define GEMB ((NN + 31) / 32)     // 3125

union H8 { __half2 h2[4]; float4 f4; };
union H4 { __half2 h2[2]; float2 f2; };

// ---------------- fused: degree histogram (+rank) || gemm1 (independent work) ----------------
__global__ __launch_bounds__(256) void k_deg_gemm1(const int* __restrict__ ei, int* __restrict__ deg,
                                                   int* __restrict__ rank, const float* __restrict__ x,
                                                   const float* __restrict__ W1, __half* __restrict__ h1) {
    if (blockIdx.x < DEGB) {
        int e = blockIdx.x * 256 + threadIdx.x;
        if (e < NE) rank[e] = atomicAdd(&deg[ei[NE + e]], 1);
        return;
    }
    // gemm1: h1 = x @ W1, stored fp16
    __shared__ float Wl[FIN * FHID];  // 8 KB
    for (int t = threadIdx.x; t < FIN * FHID / 4; t += 256)
        reinterpret_cast<float4*>(Wl)[t] = reinterpret_cast<const float4*>(W1)[t];
    __syncthreads();
    int row = (blockIdx.x - DEGB) * 32 + (threadIdx.x >> 3);
    int l = threadIdx.x & 7;  // 4 cols each
    if (row >= NN) return;
    const float4* xr = reinterpret_cast<const float4*>(x + (size_t)row * FIN);
    float4 acc = make_float4(0.f, 0.f, 0.f, 0.f);
#pragma unroll
    for (int k4 = 0; k4 < FIN / 4; ++k4) {
        float4 a4 = xr[k4];
#pragma unroll
        for (int j = 0; j < 4; ++j) {
            float a = j == 0 ? a4.x : j == 1 ? a4.y : j == 2 ? a4.z : a4.w;
            const float4 wv = *reinterpret_cast<const float4*>(Wl + (k4 * 4 + j) * FHID + l * 4);
            acc.x += a * wv.x; acc.y += a * wv.y; acc.z += a * wv.z; acc.w += a * wv.w;
        }
    }
    H4 u;
    u.h2[0] = __floats2half2_rn(acc.x, acc.y);
    u.h2[1] = __floats2half2_rn(acc.z, acc.w);
    *reinterpret_cast<float2*>(h1 + (size_t)row * FHID + l * 4) = u.f2;
}

// ---------------- dis + wave-aggregated bump allocation of CSR ranges ----------------
__global__ __launch_bounds__(256) void k_alloc(const int* __restrict__ deg, float* __restrict__ dis,
                                               int* __restrict__ off, int* __restrict__ ctr) {
    int n = blockIdx.x * 256 + threadIdx.x;
    int d = 0;
    if (n < NN) {
        d = deg[n];
        dis[n] = rsqrtf((float)d + 1.0f);
    }
    // wave-level inclusive scan of d (shfl), ONE atomic per wave
    int lane = threadIdx.x & 63;
    int incl = d;
#pragma unroll
    for (int s = 1; s < 64; s <<= 1) {
        int t = __shfl_up(incl, s, 64);
        if (lane >= s) incl += t;
    }
    int excl = incl - d;
    int base = 0;
    int tot = __shfl(incl, 63, 64);
    if (lane == 63) base = atomicAdd(ctr, tot);
    base = __shfl(base, 63, 64);
    if (n < NN) off[n] = base + excl;
}

// ---------------- CSR fill (no atomics): csr[off[dst]+rank] = src ----------------
__global__ __launch_bounds__(256) void k_fill(const int* __restrict__ ei, const int* __restrict__ off,
                                              const int* __restrict__ rank, int* __restrict__ csr) {
    int e = blockIdx.x * 256 + threadIdx.x;
    if (e >= NE) return;
    int s = ei[e];
    int d = ei[NE + e];
    csr[off[d] + rank[e]] = s;
}

// ---------------- gather layer1: hbuf = relu(agg + dis^2*h1 + b1), fp16 in/out ----------------
// 4 lanes/node, 8 cols (16 B fp16) per lane; 2-deep pipelined neighbor loop.
__global__ __launch_bounds__(256) void k_gather1(const int* __restrict__ off, const int* __restrict__ deg,
                                                 const int* __restrict__ csr, const float* __restrict__ dis,
                                                 const __half* __restrict__ h, const float* __restrict__ bias,
                                                 __half* __restrict__ out) {
    int t = blockIdx.x * 256 + threadIdx.x;
    int n = t >> 2;
    int l = t & 3;
    if (n >= NN) return;
    float dn = dis[n];
    int beg = off[n], end = beg + deg[n];
    float acc[8] = {0.f, 0.f, 0.f, 0.f, 0.f, 0.f, 0.f, 0.f};
    if (beg < end) {
        int s0 = csr[beg];
        float4 v0 = *reinterpret_cast<const float4*>(h + (size_t)s0 * FHID + l * 8);
        for (int p = beg; p < end; ++p) {
            int s1 = s0;
            float4 v1 = v0;
            if (p + 1 < end) {
                s1 = csr[p + 1];
                v1 = *reinterpret_cast<const float4*>(h + (size_t)s1 * FHID + l * 8);
            }
            float nr = dis[s0] * dn;
            const __half2* hp = reinterpret_cast<const __half2*>(&v0);
#pragma unroll
            for (int j = 0; j < 4; ++j) {
                float2 f = __half22float2(hp[j]);
                acc[2 * j] += f.x * nr;
                acc[2 * j + 1] += f.y * nr;
            }
            s0 = s1; v0 = v1;
        }
    }
    float d2 = dn * dn;
    float4 sv = *reinterpret_cast<const float4*>(h + (size_t)n * FHID + l * 8);
    const __half2* sp = reinterpret_cast<const __half2*>(&sv);
#pragma unroll
    for (int j = 0; j < 4; ++j) {
        float2 f = __half22float2(sp[j]);
        acc[2 * j] += f.x * d2;
        acc[2 * j + 1] += f.y * d2;
    }
    const float4 b0 = *reinterpret_cast<const float4*>(bias + l * 8);
    const float4 b1v = *reinterpret_cast<const float4*>(bias + l * 8 + 4);
    acc[0] += b0.x; acc[1] += b0.y; acc[2] += b0.z; acc[3] += b0.w;
    acc[4] += b1v.x; acc[5] += b1v.y; acc[6] += b1v.z; acc[7] += b1v.w;
#pragma unroll
    for (int j = 0; j < 8; ++j) acc[j] = acc[j] > 0.f ? acc[j] : 0.f;
    H8 o;
#pragma unroll
    for (int j = 0; j < 4; ++j) o.h2[j] = __floats2half2_rn(acc[2 * j], acc[2 * j + 1]);
    *reinterpret_cast<float4*>(out + (size_t)n * FHID + l * 8) = o.f4;
}

// ---------------- fused: gather(hbuf fp16) -> LDS -> @W2 + b2 -> out ----------------
// 64 nodes/block; phase A: 4 lanes/node gather; phase B: 16 cols/thread GEMM.
__global__ __launch_bounds__(256) void k_gather_mm(const int* __restrict__ off, const int* __restrict__ deg,
                                                   const int* __restrict__ csr, const float* __restrict__ dis,
                                                   const __half* __restrict__ h, const float* __restrict__ W2,
                                                   const float* __restrict__ b2, float* __restrict__ out) {
    __shared__ float WL[FHID * FIN];   // 8 KB
    __shared__ float aggL[64 * 36];    // 9 KB, stride 36 to dodge bank conflicts
    for (int t = threadIdx.x; t < FHID * FIN / 4; t += 256)
        reinterpret_cast<float4*>(WL)[t] = reinterpret_cast<const float4*>(W2)[t];

    int i = threadIdx.x >> 2;
    int l = threadIdx.x & 3;
    int n = blockIdx.x * 64 + i;
    if (n < NN) {
        float dn = dis[n];
        int beg = off[n], end = beg + deg[n];
        float acc[8] = {0.f, 0.f, 0.f, 0.f, 0.f, 0.f, 0.f, 0.f};
        if (beg < end) {
            int s0 = csr[beg];
            float4 v0 = *reinterpret_cast<const float4*>(h + (size_t)s0 * FHID + l * 8);
            for (int p = beg; p < end; ++p) {
                int s1 = s0;
                float4 v1 = v0;
                if (p + 1 < end) {
                    s1 = csr[p + 1];
                    v1 = *reinterpret_cast<const float4*>(h + (size_t)s1 * FHID + l * 8);
                }
                float nr = dis[s0] * dn;
                const __half2* hp = reinterpret_cast<const __half2*>(&v0);
#pragma unroll
                for (int j = 0; j < 4; ++j) {
                    float2 f = __half22float2(hp[j]);
                    acc[2 * j] += f.x * nr;
                    acc[2 * j + 1] += f.y * nr;
                }
                s0 = s1; v0 = v1;
            }
        }
        float d2 = dn * dn;
        float4 sv = *reinterpret_cast<const float4*>(h + (size_t)n * FHID + l * 8);
        const __half2* sp = reinterpret_cast<const __half2*>(&sv);
#pragma unroll
        for (int j = 0; j < 4; ++j) {
            float2 f = __half22float2(sp[j]);
            acc[2 * j] += f.x * d2;
            acc[2 * j + 1] += f.y * d2;
        }
        float* ar = aggL + i * 36 + l * 8;
        *reinterpret_cast<float4*>(ar) = make_float4(acc[0], acc[1], acc[2], acc[3]);
        *reinterpret_cast<float4*>(ar + 4) = make_float4(acc[4], acc[5], acc[6], acc[7]);
    }
    __syncthreads();

    // phase B: out[r] = aggL[r] @ W2 + b2
    int r = threadIdx.x >> 2;
    int n2 = blockIdx.x * 64 + r;
    if (n2 >= NN) return;
    int c0 = (threadIdx.x & 3) * 16;
    float4 a0 = *reinterpret_cast<const float4*>(b2 + c0);
    float4 a1 = *reinterpret_cast<const float4*>(b2 + c0 + 4);
    float4 a2 = *reinterpret_cast<const float4*>(b2 + c0 + 8);
    float4 a3 = *reinterpret_cast<const float4*>(b2 + c0 + 12);
    const float* ag = aggL + r * 36;
#pragma unroll
    for (int k = 0; k < FHID; ++k) {
        float a = ag[k];
        const float* wr = WL + k * FIN + c0;
        float4 w0 = *reinterpret_cast<const float4*>(wr);
        float4 w1 = *reinterpret_cast<const float4*>(wr + 4);
        float4 w2v = *reinterpret_cast<const float4*>(wr + 8);
        float4 w3 = *reinterpret_cast<const float4*>(wr + 12);
        a0.x += a * w0.x; a0.y += a * w0.y; a0.z += a * w0.z; a0.w += a * w0.w;
        a1.x += a * w1.x; a1.y += a * w1.y; a1.z += a * w1.z; a1.w += a * w1.w;
        a2.x += a * w2v.x; a2.y += a * w2v.y; a2.z += a * w2v.z; a2.w += a * w2v.w;
        a3.x += a * w3.x; a3.y += a * w3.y; a3.z += a * w3.z; a3.w += a * w3.w;
    }
    float* o = out + (size_t)n2 * FIN + c0;
    *reinterpret_cast<float4*>(o) = a0;
    *reinterpret_cast<float4*>(o + 4) = a1;
    *reinterpret_cast<float4*>(o + 8) = a2;
    *reinterpret_cast<float4*>(o + 12) = a3;
}

extern "C" void kernel_launch(void* const* d_in, const int* in_sizes, int n_in,
                              void* d_out, int out_size, void* d_ws, size_t ws_size,
                              hipStream_t stream) {
    const float* x  = (const float*)d_in[0];
    const int*   ei = (const int*)d_in[1];
    const float* W1 = (const float*)d_in[2];
    const float* b1 = (const float*)d_in[3];
    const float* W2 = (const float*)d_in[4];
    const float* b2 = (const float*)d_in[5];
    float* out = (float*)d_out;

    char* w = (char*)d_ws;
    auto align = [](size_t v) { return (v + 255) & ~(size_t)255; };
    int*    deg  = (int*)w;    w += align((size_t)NN * 4 + 4);  // ctr at deg[NN]
    int*    ctr  = deg + NN;
    int*    rank = (int*)w;    w += align((size_t)NE * 4);
    float*  dis  = (float*)w;  w += align((size_t)NN * 4);
    int*    off  = (int*)w;    w += align((size_t)NN * 4);
    int*    csr  = (int*)w;    w += align((size_t)NE * 4);
    __half* h1   = (__half*)w; w += align((size_t)NN * FHID * 2);
    __half* hbuf = (__half*)w; w += align((size_t)NN * FHID * 2);

    hipMemsetAsync(deg, 0, (size_t)NN * 4 + 4, stream);

    k_deg_gemm1<<<DEGB + GEMB, 256, 0, stream>>>(ei, deg, rank, x, W1, h1);
    k_alloc<<<(NN + 255) / 256, 256, 0, stream>>>(deg, dis, off, ctr);
    k_fill<<<DEGB, 256, 0, stream>>>(ei, off, rank, csr);
    k_gather1<<<(NN * 4 + 255) / 256, 256, 0, stream>>>(off, deg, csr, dis, h1, b1, hbuf);
    k_gather_mm<<<(NN + 63) / 64, 256, 0, stream>>>(off, deg, csr, dis, hbuf, W2, b2, out);
}

// Round 7
// 141.149 us; speedup vs baseline: 1.1459x; 1.1459x over previous
//
#include <hip/hip_runtime.h>
#include <hip/hip_fp16.h>

#define NN 100000
#define NE 1000000
#define FIN 64
#define FHID 32
#define DEGB ((NE + 255) / 256)   // 3907
#define GEMB ((NN + 31) / 32)     // 3125

union H8 { __half2 h2[4]; float4 f4; };
union H4 { __half2 h2[2]; float2 f2; };

// ---------------- fused: degree histogram (+rank) INTERLEAVED with gemm1 ----------------
// blockIdx parity interleave so atomic-bound deg blocks and BW-bound gemm blocks
// are co-resident from t=0 (R5's `blockIdx < DEGB` split dispatched all deg blocks
// first -> zero overlap).
__global__ __launch_bounds__(256) void k_deg_gemm1(const int* __restrict__ ei, int* __restrict__ deg,
                                                   int* __restrict__ rank, const float* __restrict__ x,
                                                   const float* __restrict__ W1, __half* __restrict__ h1) {
    int r = blockIdx.x;
    bool isdeg;
    int id;
    if (r < 2 * GEMB) { isdeg = !(r & 1); id = r >> 1; }
    else              { isdeg = true;     id = r - GEMB; }  // GEMB..DEGB-1
    if (isdeg) {
        int e = id * 256 + threadIdx.x;
        if (e < NE) rank[e] = atomicAdd(&deg[ei[NE + e]], 1);
        return;
    }
    // gemm1: h1 = x @ W1, stored fp16
    __shared__ float Wl[FIN * FHID];  // 8 KB
    for (int t = threadIdx.x; t < FIN * FHID / 4; t += 256)
        reinterpret_cast<float4*>(Wl)[t] = reinterpret_cast<const float4*>(W1)[t];
    __syncthreads();
    int row = id * 32 + (threadIdx.x >> 3);
    int l = threadIdx.x & 7;  // 4 cols each
    if (row >= NN) return;
    const float4* xr = reinterpret_cast<const float4*>(x + (size_t)row * FIN);
    float4 acc = make_float4(0.f, 0.f, 0.f, 0.f);
#pragma unroll
    for (int k4 = 0; k4 < FIN / 4; ++k4) {
        float4 a4 = xr[k4];
#pragma unroll
        for (int j = 0; j < 4; ++j) {
            float a = j == 0 ? a4.x : j == 1 ? a4.y : j == 2 ? a4.z : a4.w;
            const float4 wv = *reinterpret_cast<const float4*>(Wl + (k4 * 4 + j) * FHID + l * 4);
            acc.x += a * wv.x; acc.y += a * wv.y; acc.z += a * wv.z; acc.w += a * wv.w;
        }
    }
    H4 u;
    u.h2[0] = __floats2half2_rn(acc.x, acc.y);
    u.h2[1] = __floats2half2_rn(acc.z, acc.w);
    *reinterpret_cast<float2*>(h1 + (size_t)row * FHID + l * 4) = u.f2;
}

// ---------------- dis + wave-aggregated bump allocation of CSR ranges ----------------
__global__ __launch_bounds__(256) void k_alloc(const int* __restrict__ deg, float* __restrict__ dis,
                                               int* __restrict__ off, int* __restrict__ ctr) {
    int n = blockIdx.x * 256 + threadIdx.x;
    int d = 0;
    if (n < NN) {
        d = deg[n];
        dis[n] = rsqrtf((float)d + 1.0f);
    }
    int lane = threadIdx.x & 63;
    int incl = d;
#pragma unroll
    for (int s = 1; s < 64; s <<= 1) {
        int t = __shfl_up(incl, s, 64);
        if (lane >= s) incl += t;
    }
    int excl = incl - d;
    int base = 0;
    int tot = __shfl(incl, 63, 64);
    if (lane == 63) base = atomicAdd(ctr, tot);
    base = __shfl(base, 63, 64);
    if (n < NN) off[n] = base + excl;
}

// ---------------- CSR fill (no atomics): csr[off[dst]+rank] = src ----------------
__global__ __launch_bounds__(256) void k_fill(const int* __restrict__ ei, const int* __restrict__ off,
                                              const int* __restrict__ rank, int* __restrict__ csr) {
    int e = blockIdx.x * 256 + threadIdx.x;
    if (e >= NE) return;
    int s = ei[e];
    int d = ei[NE + e];
    csr[off[d] + rank[e]] = s;
}

// ---------------- gather layer1: 16 lanes/node = 4 col-lanes x 4 neighbor-lanes ----------------
// Neighbor-lane q walks p=beg+q, beg+q+4, ... -> 4 independent csr->row chains per node
// (serial depth deg/4 instead of deg). shfl_xor(4,8) reduces across q.
__global__ __launch_bounds__(256) void k_gather1(const int* __restrict__ off, const int* __restrict__ deg,
                                                 const int* __restrict__ csr, const float* __restrict__ dis,
                                                 const __half* __restrict__ h, const float* __restrict__ bias,
                                                 __half* __restrict__ out) {
    int t = blockIdx.x * 256 + threadIdx.x;
    int n = t >> 4;           // exact: NN*16 threads
    int l = t & 15;
    int q = l >> 2, c = l & 3;
    float dn = dis[n];
    int beg = off[n], end = beg + deg[n];
    float acc[8] = {0.f, 0.f, 0.f, 0.f, 0.f, 0.f, 0.f, 0.f};
    for (int p = beg + q; p < end; p += 4) {
        int s = csr[p];
        float nr = dis[s] * dn;
        float4 v = *reinterpret_cast<const float4*>(h + (size_t)s * FHID + c * 8);
        const __half2* hp = reinterpret_cast<const __half2*>(&v);
#pragma unroll
        for (int j = 0; j < 4; ++j) {
            float2 f = __half22float2(hp[j]);
            acc[2 * j] += f.x * nr;
            acc[2 * j + 1] += f.y * nr;
        }
    }
#pragma unroll
    for (int j = 0; j < 8; ++j) {
        acc[j] += __shfl_xor(acc[j], 4);
        acc[j] += __shfl_xor(acc[j], 8);
    }
    if (q == 0) {
        float d2 = dn * dn;
        float4 sv = *reinterpret_cast<const float4*>(h + (size_t)n * FHID + c * 8);
        const __half2* sp = reinterpret_cast<const __half2*>(&sv);
#pragma unroll
        for (int j = 0; j < 4; ++j) {
            float2 f = __half22float2(sp[j]);
            acc[2 * j] += f.x * d2;
            acc[2 * j + 1] += f.y * d2;
        }
        const float4 b0 = *reinterpret_cast<const float4*>(bias + c * 8);
        const float4 b1v = *reinterpret_cast<const float4*>(bias + c * 8 + 4);
        acc[0] += b0.x; acc[1] += b0.y; acc[2] += b0.z; acc[3] += b0.w;
        acc[4] += b1v.x; acc[5] += b1v.y; acc[6] += b1v.z; acc[7] += b1v.w;
#pragma unroll
        for (int j = 0; j < 8; ++j) acc[j] = acc[j] > 0.f ? acc[j] : 0.f;
        H8 o;
#pragma unroll
        for (int j = 0; j < 4; ++j) o.h2[j] = __floats2half2_rn(acc[2 * j], acc[2 * j + 1]);
        *reinterpret_cast<float4*>(out + (size_t)n * FHID + c * 8) = o.f4;
    }
}

// ---------------- fused: gather(hbuf) [16 lanes/node] -> LDS -> @W2 + b2 -> out ----------------
// 16 nodes/block; phase B: 4 cols/thread.
__global__ __launch_bounds__(256) void k_gather_mm(const int* __restrict__ off, const int* __restrict__ deg,
                                                   const int* __restrict__ csr, const float* __restrict__ dis,
                                                   const __half* __restrict__ h, const float* __restrict__ W2,
                                                   const float* __restrict__ b2, float* __restrict__ out) {
    __shared__ float WL[FHID * FIN];   // 8 KB
    __shared__ float aggL[16 * 36];    // 2.25 KB, stride 36
    for (int t = threadIdx.x; t < FHID * FIN / 4; t += 256)
        reinterpret_cast<float4*>(WL)[t] = reinterpret_cast<const float4*>(W2)[t];

    int i = threadIdx.x >> 4;  // local node 0..15
    int l = threadIdx.x & 15;
    int q = l >> 2, c = l & 3;
    int n = blockIdx.x * 16 + i;  // exact: 6250 blocks
    {
        float dn = dis[n];
        int beg = off[n], end = beg + deg[n];
        float acc[8] = {0.f, 0.f, 0.f, 0.f, 0.f, 0.f, 0.f, 0.f};
        for (int p = beg + q; p < end; p += 4) {
            int s = csr[p];
            float nr = dis[s] * dn;
            float4 v = *reinterpret_cast<const float4*>(h + (size_t)s * FHID + c * 8);
            const __half2* hp = reinterpret_cast<const __half2*>(&v);
#pragma unroll
            for (int j = 0; j < 4; ++j) {
                float2 f = __half22float2(hp[j]);
                acc[2 * j] += f.x * nr;
                acc[2 * j + 1] += f.y * nr;
            }
        }
#pragma unroll
        for (int j = 0; j < 8; ++j) {
            acc[j] += __shfl_xor(acc[j], 4);
            acc[j] += __shfl_xor(acc[j], 8);
        }
        if (q == 0) {
            float d2 = dn * dn;
            float4 sv = *reinterpret_cast<const float4*>(h + (size_t)n * FHID + c * 8);
            const __half2* sp = reinterpret_cast<const __half2*>(&sv);
#pragma unroll
            for (int j = 0; j < 4; ++j) {
                float2 f = __half22float2(sp[j]);
                acc[2 * j] += f.x * d2;
                acc[2 * j + 1] += f.y * d2;
            }
            float* ar = aggL + i * 36 + c * 8;
            *reinterpret_cast<float4*>(ar) = make_float4(acc[0], acc[1], acc[2], acc[3]);
            *reinterpret_cast<float4*>(ar + 4) = make_float4(acc[4], acc[5], acc[6], acc[7]);
        }
    }
    __syncthreads();

    // phase B: out[r] = aggL[r] @ W2 + b2   (16 rows x 64 cols, 4 cols/thread)
    int r = threadIdx.x >> 4;
    int n2 = blockIdx.x * 16 + r;
    int c0 = (threadIdx.x & 15) * 4;
    float4 a0 = *reinterpret_cast<const float4*>(b2 + c0);
    const float* ag = aggL + r * 36;
#pragma unroll
    for (int k = 0; k < FHID; ++k) {
        float a = ag[k];
        const float4 wv = *reinterpret_cast<const float4*>(WL + k * FIN + c0);
        a0.x += a * wv.x; a0.y += a * wv.y; a0.z += a * wv.z; a0.w += a * wv.w;
    }
    *reinterpret_cast<float4*>(out + (size_t)n2 * FIN + c0) = a0;
}

extern "C" void kernel_launch(void* const* d_in, const int* in_sizes, int n_in,
                              void* d_out, int out_size, void* d_ws, size_t ws_size,
                              hipStream_t stream) {
    const float* x  = (const float*)d_in[0];
    const int*   ei = (const int*)d_in[1];
    const float* W1 = (const float*)d_in[2];
    const float* b1 = (const float*)d_in[3];
    const float* W2 = (const float*)d_in[4];
    const float* b2 = (const float*)d_in[5];
    float* out = (float*)d_out;

    char* w = (char*)d_ws;
    auto align = [](size_t v) { return (v + 255) & ~(size_t)255; };
    int*    deg  = (int*)w;    w += align((size_t)NN * 4 + 4);  // ctr at deg[NN]
    int*    ctr  = deg + NN;
    int*    rank = (int*)w;    w += align((size_t)NE * 4);
    float*  dis  = (float*)w;  w += align((size_t)NN * 4);
    int*    off  = (int*)w;    w += align((size_t)NN * 4);
    int*    csr  = (int*)w;    w += align((size_t)NE * 4);
    __half* h1   = (__half*)w; w += align((size_t)NN * FHID * 2);
    __half* hbuf = (__half*)w; w += align((size_t)NN * FHID * 2);

    hipMemsetAsync(deg, 0, (size_t)NN * 4 + 4, stream);

    k_deg_gemm1<<<DEGB + GEMB, 256, 0, stream>>>(ei, deg, rank, x, W1, h1);
    k_alloc<<<(NN + 255) / 256, 256, 0, stream>>>(deg, dis, off, ctr);
    k_fill<<<DEGB, 256, 0, stream>>>(ei, off, rank, csr);
    k_gather1<<<(NN * 16) / 256, 256, 0, stream>>>(off, deg, csr, dis, h1, b1, hbuf);
    k_gather_mm<<<NN / 16, 256, 0, stream>>>(off, deg, csr, dis, hbuf, W2, b2, out);
}

// Round 8
// 137.440 us; speedup vs baseline: 1.1768x; 1.0270x over previous
//
#include <hip/hip_runtime.h>
#include <hip/hip_fp16.h>

#define NN 100000
#define NE 1000000
#define FIN 64
#define FHID 32
#define DEGB ((NE + 255) / 256)   // 3907
#define GEMB ((NN + 31) / 32)     // 3125
#define DSTRIDE 8                 // deg padded to 1 counter per 32B sector

union H8 { __half2 h2[4]; float4 f4; };
union H4 { __half2 h2[2]; float2 f2; };

// ---------------- zero deg (padded) + ctr; replaces 45us rocclr fillBuffer ----------------
__global__ __launch_bounds__(256) void k_zero(float4* __restrict__ p, int n4, int* __restrict__ ctr) {
    int i = blockIdx.x * 256 + threadIdx.x;
    int stride = gridDim.x * 256;
    float4 z = make_float4(0.f, 0.f, 0.f, 0.f);
    for (; i < n4; i += stride) p[i] = z;
    if (blockIdx.x == 0 && threadIdx.x == 0) *ctr = 0;
}

// ---------------- fused: degree histogram (+rank) INTERLEAVED with gemm1 ----------------
__global__ __launch_bounds__(256) void k_deg_gemm1(const int* __restrict__ ei, int* __restrict__ degp,
                                                   int* __restrict__ rank, const float* __restrict__ x,
                                                   const float* __restrict__ W1, __half* __restrict__ h1) {
    int r = blockIdx.x;
    bool isdeg;
    int id;
    if (r < 2 * GEMB) { isdeg = !(r & 1); id = r >> 1; }
    else              { isdeg = true;     id = r - GEMB; }
    if (isdeg) {
        int e = id * 256 + threadIdx.x;
        if (e < NE) rank[e] = atomicAdd(&degp[(size_t)ei[NE + e] * DSTRIDE], 1);
        return;
    }
    __shared__ float Wl[FIN * FHID];  // 8 KB
    for (int t = threadIdx.x; t < FIN * FHID / 4; t += 256)
        reinterpret_cast<float4*>(Wl)[t] = reinterpret_cast<const float4*>(W1)[t];
    __syncthreads();
    int row = id * 32 + (threadIdx.x >> 3);
    int l = threadIdx.x & 7;
    if (row >= NN) return;
    const float4* xr = reinterpret_cast<const float4*>(x + (size_t)row * FIN);
    float4 acc = make_float4(0.f, 0.f, 0.f, 0.f);
#pragma unroll
    for (int k4 = 0; k4 < FIN / 4; ++k4) {
        float4 a4 = xr[k4];
#pragma unroll
        for (int j = 0; j < 4; ++j) {
            float a = j == 0 ? a4.x : j == 1 ? a4.y : j == 2 ? a4.z : a4.w;
            const float4 wv = *reinterpret_cast<const float4*>(Wl + (k4 * 4 + j) * FHID + l * 4);
            acc.x += a * wv.x; acc.y += a * wv.y; acc.z += a * wv.z; acc.w += a * wv.w;
        }
    }
    H4 u;
    u.h2[0] = __floats2half2_rn(acc.x, acc.y);
    u.h2[1] = __floats2half2_rn(acc.z, acc.w);
    *reinterpret_cast<float2*>(h1 + (size_t)row * FHID + l * 4) = u.f2;
}

// ---------------- dis + wave-aggregated bump allocation; also compacts deg ----------------
__global__ __launch_bounds__(256) void k_alloc(const int* __restrict__ degp, int* __restrict__ deg,
                                               float* __restrict__ dis, int* __restrict__ off,
                                               int* __restrict__ ctr) {
    int n = blockIdx.x * 256 + threadIdx.x;
    int d = 0;
    if (n < NN) {
        d = degp[(size_t)n * DSTRIDE];
        deg[n] = d;
        dis[n] = rsqrtf((float)d + 1.0f);
    }
    int lane = threadIdx.x & 63;
    int incl = d;
#pragma unroll
    for (int s = 1; s < 64; s <<= 1) {
        int t = __shfl_up(incl, s, 64);
        if (lane >= s) incl += t;
    }
    int excl = incl - d;
    int base = 0;
    int tot = __shfl(incl, 63, 64);
    if (lane == 63) base = atomicAdd(ctr, tot);
    base = __shfl(base, 63, 64);
    if (n < NN) off[n] = base + excl;
}

// ---------------- CSR fill (no atomics): csr[off[dst]+rank] = src ----------------
__global__ __launch_bounds__(256) void k_fill(const int* __restrict__ ei, const int* __restrict__ off,
                                              const int* __restrict__ rank, int* __restrict__ csr) {
    int e = blockIdx.x * 256 + threadIdx.x;
    if (e >= NE) return;
    int s = ei[e];
    int d = ei[NE + e];
    csr[off[d] + rank[e]] = s;
}

// ---------------- gather layer1: 16 lanes/node = 4 col-lanes x 4 neighbor-lanes ----------------
__global__ __launch_bounds__(256) void k_gather1(const int* __restrict__ off, const int* __restrict__ deg,
                                                 const int* __restrict__ csr, const float* __restrict__ dis,
                                                 const __half* __restrict__ h, const float* __restrict__ bias,
                                                 __half* __restrict__ out) {
    int t = blockIdx.x * 256 + threadIdx.x;
    int n = t >> 4;
    int l = t & 15;
    int q = l >> 2, c = l & 3;
    float dn = dis[n];
    int beg = off[n], end = beg + deg[n];
    float acc[8] = {0.f, 0.f, 0.f, 0.f, 0.f, 0.f, 0.f, 0.f};
    for (int p = beg + q; p < end; p += 4) {
        int s = csr[p];
        float nr = dis[s] * dn;
        float4 v = *reinterpret_cast<const float4*>(h + (size_t)s * FHID + c * 8);
        const __half2* hp = reinterpret_cast<const __half2*>(&v);
#pragma unroll
        for (int j = 0; j < 4; ++j) {
            float2 f = __half22float2(hp[j]);
            acc[2 * j] += f.x * nr;
            acc[2 * j + 1] += f.y * nr;
        }
    }
#pragma unroll
    for (int j = 0; j < 8; ++j) {
        acc[j] += __shfl_xor(acc[j], 4);
        acc[j] += __shfl_xor(acc[j], 8);
    }
    if (q == 0) {
        float d2 = dn * dn;
        float4 sv = *reinterpret_cast<const float4*>(h + (size_t)n * FHID + c * 8);
        const __half2* sp = reinterpret_cast<const __half2*>(&sv);
#pragma unroll
        for (int j = 0; j < 4; ++j) {
            float2 f = __half22float2(sp[j]);
            acc[2 * j] += f.x * d2;
            acc[2 * j + 1] += f.y * d2;
        }
        const float4 b0 = *reinterpret_cast<const float4*>(bias + c * 8);
        const float4 b1v = *reinterpret_cast<const float4*>(bias + c * 8 + 4);
        acc[0] += b0.x; acc[1] += b0.y; acc[2] += b0.z; acc[3] += b0.w;
        acc[4] += b1v.x; acc[5] += b1v.y; acc[6] += b1v.z; acc[7] += b1v.w;
#pragma unroll
        for (int j = 0; j < 8; ++j) acc[j] = acc[j] > 0.f ? acc[j] : 0.f;
        H8 o;
#pragma unroll
        for (int j = 0; j < 4; ++j) o.h2[j] = __floats2half2_rn(acc[2 * j], acc[2 * j + 1]);
        *reinterpret_cast<float4*>(out + (size_t)n * FHID + c * 8) = o.f4;
    }
}

// ---------------- fused: gather(hbuf) [16 lanes/node] -> LDS -> @W2 + b2 -> out ----------------
__global__ __launch_bounds__(256) void k_gather_mm(const int* __restrict__ off, const int* __restrict__ deg,
                                                   const int* __restrict__ csr, const float* __restrict__ dis,
                                                   const __half* __restrict__ h, const float* __restrict__ W2,
                                                   const float* __restrict__ b2, float* __restrict__ out) {
    __shared__ float WL[FHID * FIN];   // 8 KB
    __shared__ float aggL[16 * 36];    // 2.25 KB
    for (int t = threadIdx.x; t < FHID * FIN / 4; t += 256)
        reinterpret_cast<float4*>(WL)[t] = reinterpret_cast<const float4*>(W2)[t];

    int i = threadIdx.x >> 4;
    int l = threadIdx.x & 15;
    int q = l >> 2, c = l & 3;
    int n = blockIdx.x * 16 + i;
    {
        float dn = dis[n];
        int beg = off[n], end = beg + deg[n];
        float acc[8] = {0.f, 0.f, 0.f, 0.f, 0.f, 0.f, 0.f, 0.f};
        for (int p = beg + q; p < end; p += 4) {
            int s = csr[p];
            float nr = dis[s] * dn;
            float4 v = *reinterpret_cast<const float4*>(h + (size_t)s * FHID + c * 8);
            const __half2* hp = reinterpret_cast<const __half2*>(&v);
#pragma unroll
            for (int j = 0; j < 4; ++j) {
                float2 f = __half22float2(hp[j]);
                acc[2 * j] += f.x * nr;
                acc[2 * j + 1] += f.y * nr;
            }
        }
#pragma unroll
        for (int j = 0; j < 8; ++j) {
            acc[j] += __shfl_xor(acc[j], 4);
            acc[j] += __shfl_xor(acc[j], 8);
        }
        if (q == 0) {
            float d2 = dn * dn;
            float4 sv = *reinterpret_cast<const float4*>(h + (size_t)n * FHID + c * 8);
            const __half2* sp = reinterpret_cast<const __half2*>(&sv);
#pragma unroll
            for (int j = 0; j < 4; ++j) {
                float2 f = __half22float2(sp[j]);
                acc[2 * j] += f.x * d2;
                acc[2 * j + 1] += f.y * d2;
            }
            float* ar = aggL + i * 36 + c * 8;
            *reinterpret_cast<float4*>(ar) = make_float4(acc[0], acc[1], acc[2], acc[3]);
            *reinterpret_cast<float4*>(ar + 4) = make_float4(acc[4], acc[5], acc[6], acc[7]);
        }
    }
    __syncthreads();

    int r = threadIdx.x >> 4;
    int n2 = blockIdx.x * 16 + r;
    int c0 = (threadIdx.x & 15) * 4;
    float4 a0 = *reinterpret_cast<const float4*>(b2 + c0);
    const float* ag = aggL + r * 36;
#pragma unroll
    for (int k = 0; k < FHID; ++k) {
        float a = ag[k];
        const float4 wv = *reinterpret_cast<const float4*>(WL + k * FIN + c0);
        a0.x += a * wv.x; a0.y += a * wv.y; a0.z += a * wv.z; a0.w += a * wv.w;
    }
    *reinterpret_cast<float4*>(out + (size_t)n2 * FIN + c0) = a0;
}

extern "C" void kernel_launch(void* const* d_in, const int* in_sizes, int n_in,
                              void* d_out, int out_size, void* d_ws, size_t ws_size,
                              hipStream_t stream) {
    const float* x  = (const float*)d_in[0];
    const int*   ei = (const int*)d_in[1];
    const float* W1 = (const float*)d_in[2];
    const float* b1 = (const float*)d_in[3];
    const float* W2 = (const float*)d_in[4];
    const float* b2 = (const float*)d_in[5];
    float* out = (float*)d_out;

    char* w = (char*)d_ws;
    auto align = [](size_t v) { return (v + 255) & ~(size_t)255; };
    int*    degp = (int*)w;    w += align((size_t)NN * DSTRIDE * 4);  // padded: 1 counter / 32B
    int*    deg  = (int*)w;    w += align((size_t)NN * 4 + 4);        // compact copy; ctr at deg[NN]
    int*    ctr  = deg + NN;
    int*    rank = (int*)w;    w += align((size_t)NE * 4);
    float*  dis  = (float*)w;  w += align((size_t)NN * 4);
    int*    off  = (int*)w;    w += align((size_t)NN * 4);
    int*    csr  = (int*)w;    w += align((size_t)NE * 4);
    __half* h1   = (__half*)w; w += align((size_t)NN * FHID * 2);
    __half* hbuf = (__half*)w; w += align((size_t)NN * FHID * 2);

    // zero padded deg (3.2 MB) + ctr with a real kernel (rocclr fillBuffer was 45us!)
    k_zero<<<512, 256, 0, stream>>>((float4*)degp, NN * DSTRIDE / 4, ctr);

    k_deg_gemm1<<<DEGB + GEMB, 256, 0, stream>>>(ei, degp, rank, x, W1, h1);
    k_alloc<<<(NN + 255) / 256, 256, 0, stream>>>(degp, deg, dis, off, ctr);
    k_fill<<<DEGB, 256, 0, stream>>>(ei, off, rank, csr);
    k_gather1<<<(NN * 16) / 256, 256, 0, stream>>>(off, deg, csr, dis, h1, b1, hbuf);
    k_gather_mm<<<NN / 16, 256, 0, stream>>>(off, deg, csr, dis, hbuf, W2, b2, out);
}

// Round 9
// 134.992 us; speedup vs baseline: 1.1981x; 1.0181x over previous
//
#include <hip/hip_runtime.h>
#include <hip/hip_fp16.h>

#define NN 100000
#define NE 1000000
#define FIN 64
#define FHID 32
#define NB 782               // dst>>7 buckets (100000/128)
#define BNODES 128
#define NCH 64               // edge chunks (pass A/C blocks)
#define CH ((NE + NCH - 1) / NCH)   // 15625; 64*15625 == NE exactly
#define GEMB ((NN + 31) / 32)       // 3125

union H8 { __half2 h2[4]; float4 f4; };
union H4 { __half2 h2[2]; float2 f2; };

// ---------------- pass A: per-chunk LDS bucket histogram (zero global atomics) ----------------
__global__ __launch_bounds__(256) void k_bhist(const int* __restrict__ dst, int* __restrict__ phistT) {
    __shared__ int lh[NB];
    for (int i = threadIdx.x; i < NB; i += 256) lh[i] = 0;
    __syncthreads();
    int k = blockIdx.x;
    int e0 = k * CH, e1 = e0 + CH;
    for (int e = e0 + threadIdx.x; e < e1; e += 256) atomicAdd(&lh[dst[e] >> 7], 1);
    __syncthreads();
    for (int b = threadIdx.x; b < NB; b += 256) phistT[b * NCH + k] = lh[b];
}

// ---------------- pass B: per-bucket chunk-prefix + cross-bucket scan ----------------
__global__ __launch_bounds__(1024) void k_scan(int* __restrict__ phistT, int* __restrict__ bbase,
                                               int* __restrict__ off) {
    __shared__ int stot[1024];
    int b = threadIdx.x;
    int tot = 0;
    if (b < NB) {
        int base = b * NCH;
#pragma unroll 8
        for (int k = 0; k < NCH; ++k) {
            int v = phistT[base + k];
            phistT[base + k] = tot;  // exclusive prefix within bucket
            tot += v;
        }
    }
    stot[b] = tot;
    __syncthreads();
    for (int d = 1; d < 1024; d <<= 1) {
        int t = (b >= d) ? stot[b - d] : 0;
        __syncthreads();
        stot[b] += t;
        __syncthreads();
    }
    if (b < NB) bbase[b] = stot[b] - tot;  // exclusive bucket base
    if (b == 0) { bbase[NB] = NE; off[NN] = NE; }
}

// ---------------- pass C: bucket-scatter (LDS ranks) || gemm1 ----------------
__global__ __launch_bounds__(256) void k_scatter_gemm1(const int* __restrict__ ei,
                                                       const int* __restrict__ phistT,
                                                       const int* __restrict__ bbase,
                                                       int2* __restrict__ ebuf,
                                                       const float* __restrict__ x,
                                                       const float* __restrict__ W1,
                                                       __half* __restrict__ h1) {
    if (blockIdx.x < NCH) {
        __shared__ int lh[NB];
        __shared__ int lbase[NB];
        int k = blockIdx.x;
        for (int b = threadIdx.x; b < NB; b += 256) {
            lh[b] = 0;
            lbase[b] = bbase[b] + phistT[b * NCH + k];
        }
        __syncthreads();
        int e0 = k * CH, e1 = e0 + CH;
        for (int e = e0 + threadIdx.x; e < e1; e += 256) {
            int s = ei[e], d = ei[NE + e];
            int bb = d >> 7;
            int r = atomicAdd(&lh[bb], 1);  // LDS atomic: unique rank within (chunk,bucket)
            ebuf[lbase[bb] + r] = make_int2(s, d);
        }
        return;
    }
    // gemm1: h1 = x @ W1 (fp16 out) on remaining blocks — fills CUs the 64 scatter blocks don't use
    __shared__ float Wl[FIN * FHID];  // 8 KB
    for (int t = threadIdx.x; t < FIN * FHID / 4; t += 256)
        reinterpret_cast<float4*>(Wl)[t] = reinterpret_cast<const float4*>(W1)[t];
    __syncthreads();
    int row = (int)(blockIdx.x - NCH) * 32 + (threadIdx.x >> 3);
    int l = threadIdx.x & 7;
    if (row >= NN) return;
    const float4* xr = reinterpret_cast<const float4*>(x + (size_t)row * FIN);
    float4 acc = make_float4(0.f, 0.f, 0.f, 0.f);
#pragma unroll
    for (int k4 = 0; k4 < FIN / 4; ++k4) {
        float4 a4 = xr[k4];
#pragma unroll
        for (int j = 0; j < 4; ++j) {
            float a = j == 0 ? a4.x : j == 1 ? a4.y : j == 2 ? a4.z : a4.w;
            const float4 wv = *reinterpret_cast<const float4*>(Wl + (k4 * 4 + j) * FHID + l * 4);
            acc.x += a * wv.x; acc.y += a * wv.y; acc.z += a * wv.z; acc.w += a * wv.w;
        }
    }
    H4 u;
    u.h2[0] = __floats2half2_rn(acc.x, acc.y);
    u.h2[1] = __floats2half2_rn(acc.z, acc.w);
    *reinterpret_cast<float2*>(h1 + (size_t)row * FHID + l * 4) = u.f2;
}

// ---------------- pass D: per-bucket exact CSR + off + dis (node-ordered) ----------------
__global__ __launch_bounds__(256) void k_csr(const int2* __restrict__ ebuf, const int* __restrict__ bbase,
                                             int* __restrict__ off, float* __restrict__ dis,
                                             int* __restrict__ csr) {
    __shared__ int nh[BNODES];
    __shared__ int ofl[BNODES];
    int b = blockIdx.x;
    int n0 = b * BNODES;
    int ebeg = bbase[b], eend = bbase[b + 1];
    int ld = threadIdx.x;
    if (ld < BNODES) nh[ld] = 0;
    __syncthreads();
    for (int e = ebeg + threadIdx.x; e < eend; e += 256) atomicAdd(&nh[ebuf[e].y - n0], 1);
    __syncthreads();
    int dval = (ld < BNODES) ? nh[ld] : 0;
    if (ld < BNODES) ofl[ld] = dval;
    __syncthreads();
    for (int s = 1; s < BNODES; s <<= 1) {
        int t = 0;
        if (ld < BNODES && ld >= s) t = ofl[ld - s];
        __syncthreads();
        if (ld < BNODES) ofl[ld] += t;
        __syncthreads();
    }
    if (ld < BNODES) {
        ofl[ld] -= dval;  // exclusive scan
        int n = n0 + ld;
        if (n < NN) {
            off[n] = ebeg + ofl[ld];
            dis[n] = rsqrtf((float)dval + 1.0f);
        }
        nh[ld] = 0;  // reuse as per-node cursor
    }
    __syncthreads();
    for (int e = ebeg + threadIdx.x; e < eend; e += 256) {
        int2 sd = ebuf[e];
        int ldd = sd.y - n0;
        int r = atomicAdd(&nh[ldd], 1);
        csr[ebeg + ofl[ldd] + r] = sd.x;
    }
}

// ---------------- gather layer1: 16 lanes/node = 4 col-lanes x 4 neighbor-lanes ----------------
__global__ __launch_bounds__(256) void k_gather1(const int* __restrict__ off, const int* __restrict__ csr,
                                                 const float* __restrict__ dis,
                                                 const __half* __restrict__ h, const float* __restrict__ bias,
                                                 __half* __restrict__ out) {
    int t = blockIdx.x * 256 + threadIdx.x;
    int n = t >> 4;
    int l = t & 15;
    int q = l >> 2, c = l & 3;
    float dn = dis[n];
    int beg = off[n], end = off[n + 1];
    float acc[8] = {0.f, 0.f, 0.f, 0.f, 0.f, 0.f, 0.f, 0.f};
    for (int p = beg + q; p < end; p += 4) {
        int s = csr[p];
        float nr = dis[s] * dn;
        float4 v = *reinterpret_cast<const float4*>(h + (size_t)s * FHID + c * 8);
        const __half2* hp = reinterpret_cast<const __half2*>(&v);
#pragma unroll
        for (int j = 0; j < 4; ++j) {
            float2 f = __half22float2(hp[j]);
            acc[2 * j] += f.x * nr;
            acc[2 * j + 1] += f.y * nr;
        }
    }
#pragma unroll
    for (int j = 0; j < 8; ++j) {
        acc[j] += __shfl_xor(acc[j], 4);
        acc[j] += __shfl_xor(acc[j], 8);
    }
    if (q == 0) {
        float d2 = dn * dn;
        float4 sv = *reinterpret_cast<const float4*>(h + (size_t)n * FHID + c * 8);
        const __half2* sp = reinterpret_cast<const __half2*>(&sv);
#pragma unroll
        for (int j = 0; j < 4; ++j) {
            float2 f = __half22float2(sp[j]);
            acc[2 * j] += f.x * d2;
            acc[2 * j + 1] += f.y * d2;
        }
        const float4 b0 = *reinterpret_cast<const float4*>(bias + c * 8);
        const float4 b1v = *reinterpret_cast<const float4*>(bias + c * 8 + 4);
        acc[0] += b0.x; acc[1] += b0.y; acc[2] += b0.z; acc[3] += b0.w;
        acc[4] += b1v.x; acc[5] += b1v.y; acc[6] += b1v.z; acc[7] += b1v.w;
#pragma unroll
        for (int j = 0; j < 8; ++j) acc[j] = acc[j] > 0.f ? acc[j] : 0.f;
        H8 o;
#pragma unroll
        for (int j = 0; j < 4; ++j) o.h2[j] = __floats2half2_rn(acc[2 * j], acc[2 * j + 1]);
        *reinterpret_cast<float4*>(out + (size_t)n * FHID + c * 8) = o.f4;
    }
}

// ---------------- fused: gather(hbuf) -> LDS -> @W2 + b2 -> out ----------------
__global__ __launch_bounds__(256) void k_gather_mm(const int* __restrict__ off, const int* __restrict__ csr,
                                                   const float* __restrict__ dis,
                                                   const __half* __restrict__ h, const float* __restrict__ W2,
                                                   const float* __restrict__ b2, float* __restrict__ out) {
    __shared__ float WL[FHID * FIN];   // 8 KB
    __shared__ float aggL[16 * 36];
    for (int t = threadIdx.x; t < FHID * FIN / 4; t += 256)
        reinterpret_cast<float4*>(WL)[t] = reinterpret_cast<const float4*>(W2)[t];

    int i = threadIdx.x >> 4;
    int l = threadIdx.x & 15;
    int q = l >> 2, c = l & 3;
    int n = blockIdx.x * 16 + i;
    {
        float dn = dis[n];
        int beg = off[n], end = off[n + 1];
        float acc[8] = {0.f, 0.f, 0.f, 0.f, 0.f, 0.f, 0.f, 0.f};
        for (int p = beg + q; p < end; p += 4) {
            int s = csr[p];
            float nr = dis[s] * dn;
            float4 v = *reinterpret_cast<const float4*>(h + (size_t)s * FHID + c * 8);
            const __half2* hp = reinterpret_cast<const __half2*>(&v);
#pragma unroll
            for (int j = 0; j < 4; ++j) {
                float2 f = __half22float2(hp[j]);
                acc[2 * j] += f.x * nr;
                acc[2 * j + 1] += f.y * nr;
            }
        }
#pragma unroll
        for (int j = 0; j < 8; ++j) {
            acc[j] += __shfl_xor(acc[j], 4);
            acc[j] += __shfl_xor(acc[j], 8);
        }
        if (q == 0) {
            float d2 = dn * dn;
            float4 sv = *reinterpret_cast<const float4*>(h + (size_t)n * FHID + c * 8);
            const __half2* sp = reinterpret_cast<const __half2*>(&sv);
#pragma unroll
            for (int j = 0; j < 4; ++j) {
                float2 f = __half22float2(sp[j]);
                acc[2 * j] += f.x * d2;
                acc[2 * j + 1] += f.y * d2;
            }
            float* ar = aggL + i * 36 + c * 8;
            *reinterpret_cast<float4*>(ar) = make_float4(acc[0], acc[1], acc[2], acc[3]);
            *reinterpret_cast<float4*>(ar + 4) = make_float4(acc[4], acc[5], acc[6], acc[7]);
        }
    }
    __syncthreads();

    int r = threadIdx.x >> 4;
    int n2 = blockIdx.x * 16 + r;
    int c0 = (threadIdx.x & 15) * 4;
    float4 a0 = *reinterpret_cast<const float4*>(b2 + c0);
    const float* ag = aggL + r * 36;
#pragma unroll
    for (int k = 0; k < FHID; ++k) {
        float a = ag[k];
        const float4 wv = *reinterpret_cast<const float4*>(WL + k * FIN + c0);
        a0.x += a * wv.x; a0.y += a * wv.y; a0.z += a * wv.z; a0.w += a * wv.w;
    }
    *reinterpret_cast<float4*>(out + (size_t)n2 * FIN + c0) = a0;
}

extern "C" void kernel_launch(void* const* d_in, const int* in_sizes, int n_in,
                              void* d_out, int out_size, void* d_ws, size_t ws_size,
                              hipStream_t stream) {
    const float* x  = (const float*)d_in[0];
    const int*   ei = (const int*)d_in[1];
    const float* W1 = (const float*)d_in[2];
    const float* b1 = (const float*)d_in[3];
    const float* W2 = (const float*)d_in[4];
    const float* b2 = (const float*)d_in[5];
    float* out = (float*)d_out;

    char* w = (char*)d_ws;
    auto align = [](size_t v) { return (v + 255) & ~(size_t)255; };
    int*    phistT = (int*)w;    w += align((size_t)NB * NCH * 4);
    int*    bbase  = (int*)w;    w += align((size_t)(NB + 1) * 4);
    int2*   ebuf   = (int2*)w;   w += align((size_t)NE * 8);
    int*    off    = (int*)w;    w += align((size_t)(NN + 1) * 4);
    float*  dis    = (float*)w;  w += align((size_t)NN * 4);
    int*    csr    = (int*)w;    w += align((size_t)NE * 4);
    __half* h1     = (__half*)w; w += align((size_t)NN * FHID * 2);
    __half* hbuf   = (__half*)w; w += align((size_t)NN * FHID * 2);

    const int* dst = ei + NE;
    k_bhist<<<NCH, 256, 0, stream>>>(dst, phistT);
    k_scan<<<1, 1024, 0, stream>>>(phistT, bbase, off);
    k_scatter_gemm1<<<NCH + GEMB, 256, 0, stream>>>(ei, phistT, bbase, ebuf, x, W1, h1);
    k_csr<<<NB, 256, 0, stream>>>(ebuf, bbase, off, dis, csr);
    k_gather1<<<(NN * 16) / 256, 256, 0, stream>>>(off, csr, dis, h1, b1, hbuf);
    k_gather_mm<<<NN / 16, 256, 0, stream>>>(off, csr, dis, hbuf, W2, b2, out);
}

// Round 10
// 95.031 us; speedup vs baseline: 1.7020x; 1.4205x over previous
//
#include <hip/hip_runtime.h>
#include <hip/hip_fp16.h>

#define NN 100000
#define NE 1000000
#define FIN 64
#define FHID 32
#define NB 782                    // dst>>7 buckets
#define BNODES 128
#define NCH 256                   // edge chunks
#define CH ((NE + NCH - 1) / NCH) // 3907
#define GEMB ((NN + 31) / 32)     // 3125

union H8 { __half2 h2[4]; float4 f4; };
union H4 { __half2 h2[2]; float2 f2; };

// ---------------- pass A: per-chunk LDS bucket histogram; phist[k][b] chunk-major ----------------
__global__ __launch_bounds__(256) void k_bhist(const int* __restrict__ dst, int* __restrict__ phist) {
    __shared__ int lh[NB];
    for (int i = threadIdx.x; i < NB; i += 256) lh[i] = 0;
    __syncthreads();
    int k = blockIdx.x;
    int e0 = k * CH, e1 = min(e0 + CH, NE);
    for (int e = e0 + threadIdx.x; e < e1; e += 256) atomicAdd(&lh[dst[e] >> 7], 1);
    __syncthreads();
    for (int b = threadIdx.x; b < NB; b += 256) phist[(size_t)k * NB + b] = lh[b];  // coalesced
}

// ---------------- pass B1: per-bucket scan over 256 chunks (one block per bucket) ----------------
__global__ __launch_bounds__(256) void k_bscan(int* __restrict__ phist, int* __restrict__ btot) {
    int b = blockIdx.x;
    int k = threadIdx.x;
    int v = phist[(size_t)k * NB + b];
    int lane = k & 63, wv = k >> 6;
    int incl = v;
#pragma unroll
    for (int s = 1; s < 64; s <<= 1) {
        int t = __shfl_up(incl, s, 64);
        if (lane >= s) incl += t;
    }
    __shared__ int wt[4];
    if (lane == 63) wt[wv] = incl;
    __syncthreads();
    int add = 0;
#pragma unroll
    for (int w = 0; w < 4; ++w) add += (w < wv) ? wt[w] : 0;
    phist[(size_t)k * NB + b] = add + incl - v;  // exclusive prefix within bucket
    if (k == 255) btot[b] = add + incl;
}

// ---------------- pass B2: cross-bucket scan (1 block) ----------------
__global__ __launch_bounds__(1024) void k_bbase(const int* __restrict__ btot, int* __restrict__ bbase,
                                                int* __restrict__ off) {
    __shared__ int s[1024];
    int b = threadIdx.x;
    int v = (b < NB) ? btot[b] : 0;
    s[b] = v;
    __syncthreads();
    for (int d = 1; d < 1024; d <<= 1) {
        int t = (b >= d) ? s[b - d] : 0;
        __syncthreads();
        s[b] += t;
        __syncthreads();
    }
    if (b < NB) bbase[b] = s[b] - v;
    if (b == 0) { bbase[NB] = NE; off[NN] = NE; }
}

// ---------------- pass C: bucket-scatter (packed 4B) || gemm1 ----------------
__global__ __launch_bounds__(256) void k_scatter_gemm1(const int* __restrict__ ei,
                                                       const int* __restrict__ phist,
                                                       const int* __restrict__ bbase,
                                                       int* __restrict__ ebuf,
                                                       const float* __restrict__ x,
                                                       const float* __restrict__ W1,
                                                       __half* __restrict__ h1) {
    int r = blockIdx.x;
    bool issc;
    int id;
    if (r < 2 * NCH) { issc = !(r & 1); id = r >> 1; }
    else             { issc = false;    id = r - NCH; }
    if (issc) {
        __shared__ int lh[NB];
        __shared__ int lbase[NB];
        int k = id;
        for (int b = threadIdx.x; b < NB; b += 256) {
            lh[b] = 0;
            lbase[b] = bbase[b] + phist[(size_t)k * NB + b];  // coalesced
        }
        __syncthreads();
        int e0 = k * CH, e1 = min(e0 + CH, NE);
        for (int e = e0 + threadIdx.x; e < e1; e += 256) {
            int s = ei[e], d = ei[NE + e];
            int bb = d >> 7;
            int rr = atomicAdd(&lh[bb], 1);  // LDS atomic rank within (chunk,bucket)
            ebuf[lbase[bb] + rr] = s * BNODES + (d & 127);  // packed
        }
        return;
    }
    // gemm1: h1 = x @ W1 (fp16 out)
    __shared__ float Wl[FIN * FHID];  // 8 KB
    for (int t = threadIdx.x; t < FIN * FHID / 4; t += 256)
        reinterpret_cast<float4*>(Wl)[t] = reinterpret_cast<const float4*>(W1)[t];
    __syncthreads();
    int row = id * 32 + (threadIdx.x >> 3);
    int l = threadIdx.x & 7;
    if (row >= NN) return;
    const float4* xr = reinterpret_cast<const float4*>(x + (size_t)row * FIN);
    float4 acc = make_float4(0.f, 0.f, 0.f, 0.f);
#pragma unroll
    for (int k4 = 0; k4 < FIN / 4; ++k4) {
        float4 a4 = xr[k4];
#pragma unroll
        for (int j = 0; j < 4; ++j) {
            float a = j == 0 ? a4.x : j == 1 ? a4.y : j == 2 ? a4.z : a4.w;
            const float4 wv = *reinterpret_cast<const float4*>(Wl + (k4 * 4 + j) * FHID + l * 4);
            acc.x += a * wv.x; acc.y += a * wv.y; acc.z += a * wv.z; acc.w += a * wv.w;
        }
    }
    H4 u;
    u.h2[0] = __floats2half2_rn(acc.x, acc.y);
    u.h2[1] = __floats2half2_rn(acc.z, acc.w);
    *reinterpret_cast<float2*>(h1 + (size_t)row * FHID + l * 4) = u.f2;
}

// ---------------- pass D: per-bucket node CSR + off + dis ----------------
__global__ __launch_bounds__(256) void k_csr(const int* __restrict__ ebuf, const int* __restrict__ bbase,
                                             int* __restrict__ off, float* __restrict__ dis,
                                             int* __restrict__ csr) {
    __shared__ int nh[BNODES];
    __shared__ int ofl[BNODES];
    int b = blockIdx.x;
    int n0 = b * BNODES;
    int ebeg = bbase[b], eend = bbase[b + 1];
    int ld = threadIdx.x;
    if (ld < BNODES) nh[ld] = 0;
    __syncthreads();
    for (int e = ebeg + threadIdx.x; e < eend; e += 256) atomicAdd(&nh[ebuf[e] & 127], 1);
    __syncthreads();
    int dval = (ld < BNODES) ? nh[ld] : 0;
    if (ld < BNODES) ofl[ld] = dval;
    __syncthreads();
    for (int s = 1; s < BNODES; s <<= 1) {
        int t = 0;
        if (ld < BNODES && ld >= s) t = ofl[ld - s];
        __syncthreads();
        if (ld < BNODES) ofl[ld] += t;
        __syncthreads();
    }
    if (ld < BNODES) {
        ofl[ld] -= dval;
        int n = n0 + ld;
        if (n < NN) {
            off[n] = ebeg + ofl[ld];
            dis[n] = rsqrtf((float)dval + 1.0f);
        }
        nh[ld] = 0;
    }
    __syncthreads();
    for (int e = ebeg + threadIdx.x; e < eend; e += 256) {
        int v = ebuf[e];
        int ldd = v & 127;
        int r = atomicAdd(&nh[ldd], 1);
        csr[ebeg + ofl[ldd] + r] = v >> 7;
    }
}

// ---------------- gather layer1: 16 lanes/node, csr prefetch ----------------
__global__ __launch_bounds__(256) void k_gather1(const int* __restrict__ off, const int* __restrict__ csr,
                                                 const float* __restrict__ dis,
                                                 const __half* __restrict__ h, const float* __restrict__ bias,
                                                 __half* __restrict__ out) {
    int t = blockIdx.x * 256 + threadIdx.x;
    int n = t >> 4;
    int l = t & 15;
    int q = l >> 2, c = l & 3;
    float dn = dis[n];
    int beg = off[n], end = off[n + 1];
    float acc[8] = {0.f, 0.f, 0.f, 0.f, 0.f, 0.f, 0.f, 0.f};
    int p = beg + q;
    int s = (p < end) ? csr[p] : 0;
    for (; p < end; p += 4) {
        int scur = s;
        if (p + 4 < end) s = csr[p + 4];  // prefetch next index before consuming row
        float nr = dis[scur] * dn;
        float4 v = *reinterpret_cast<const float4*>(h + (size_t)scur * FHID + c * 8);
        const __half2* hp = reinterpret_cast<const __half2*>(&v);
#pragma unroll
        for (int j = 0; j < 4; ++j) {
            float2 f = __half22float2(hp[j]);
            acc[2 * j] += f.x * nr;
            acc[2 * j + 1] += f.y * nr;
        }
    }
#pragma unroll
    for (int j = 0; j < 8; ++j) {
        acc[j] += __shfl_xor(acc[j], 4);
        acc[j] += __shfl_xor(acc[j], 8);
    }
    if (q == 0) {
        float d2 = dn * dn;
        float4 sv = *reinterpret_cast<const float4*>(h + (size_t)n * FHID + c * 8);
        const __half2* sp = reinterpret_cast<const __half2*>(&sv);
#pragma unroll
        for (int j = 0; j < 4; ++j) {
            float2 f = __half22float2(sp[j]);
            acc[2 * j] += f.x * d2;
            acc[2 * j + 1] += f.y * d2;
        }
        const float4 b0 = *reinterpret_cast<const float4*>(bias + c * 8);
        const float4 b1v = *reinterpret_cast<const float4*>(bias + c * 8 + 4);
        acc[0] += b0.x; acc[1] += b0.y; acc[2] += b0.z; acc[3] += b0.w;
        acc[4] += b1v.x; acc[5] += b1v.y; acc[6] += b1v.z; acc[7] += b1v.w;
#pragma unroll
        for (int j = 0; j < 8; ++j) acc[j] = acc[j] > 0.f ? acc[j] : 0.f;
        H8 o;
#pragma unroll
        for (int j = 0; j < 4; ++j) o.h2[j] = __floats2half2_rn(acc[2 * j], acc[2 * j + 1]);
        *reinterpret_cast<float4*>(out + (size_t)n * FHID + c * 8) = o.f4;
    }
}

// ---------------- fused: gather(hbuf) -> LDS -> @W2 + b2 -> out ----------------
__global__ __launch_bounds__(256) void k_gather_mm(const int* __restrict__ off, const int* __restrict__ csr,
                                                   const float* __restrict__ dis,
                                                   const __half* __restrict__ h, const float* __restrict__ W2,
                                                   const float* __restrict__ b2, float* __restrict__ out) {
    __shared__ float WL[FHID * FIN];   // 8 KB
    __shared__ float aggL[16 * 36];
    for (int t = threadIdx.x; t < FHID * FIN / 4; t += 256)
        reinterpret_cast<float4*>(WL)[t] = reinterpret_cast<const float4*>(W2)[t];

    int i = threadIdx.x >> 4;
    int l = threadIdx.x & 15;
    int q = l >> 2, c = l & 3;
    int n = blockIdx.x * 16 + i;
    {
        float dn = dis[n];
        int beg = off[n], end = off[n + 1];
        float acc[8] = {0.f, 0.f, 0.f, 0.f, 0.f, 0.f, 0.f, 0.f};
        int p = beg + q;
        int s = (p < end) ? csr[p] : 0;
        for (; p < end; p += 4) {
            int scur = s;
            if (p + 4 < end) s = csr[p + 4];
            float nr = dis[scur] * dn;
            float4 v = *reinterpret_cast<const float4*>(h + (size_t)scur * FHID + c * 8);
            const __half2* hp = reinterpret_cast<const __half2*>(&v);
#pragma unroll
            for (int j = 0; j < 4; ++j) {
                float2 f = __half22float2(hp[j]);
                acc[2 * j] += f.x * nr;
                acc[2 * j + 1] += f.y * nr;
            }
        }
#pragma unroll
        for (int j = 0; j < 8; ++j) {
            acc[j] += __shfl_xor(acc[j], 4);
            acc[j] += __shfl_xor(acc[j], 8);
        }
        if (q == 0) {
            float d2 = dn * dn;
            float4 sv = *reinterpret_cast<const float4*>(h + (size_t)n * FHID + c * 8);
            const __half2* sp = reinterpret_cast<const __half2*>(&sv);
#pragma unroll
            for (int j = 0; j < 4; ++j) {
                float2 f = __half22float2(sp[j]);
                acc[2 * j] += f.x * d2;
                acc[2 * j + 1] += f.y * d2;
            }
            float* ar = aggL + i * 36 + c * 8;
            *reinterpret_cast<float4*>(ar) = make_float4(acc[0], acc[1], acc[2], acc[3]);
            *reinterpret_cast<float4*>(ar + 4) = make_float4(acc[4], acc[5], acc[6], acc[7]);
        }
    }
    __syncthreads();

    int r = threadIdx.x >> 4;
    int n2 = blockIdx.x * 16 + r;
    int c0 = (threadIdx.x & 15) * 4;
    float4 a0 = *reinterpret_cast<const float4*>(b2 + c0);
    const float* ag = aggL + r * 36;
#pragma unroll
    for (int k = 0; k < FHID; ++k) {
        float a = ag[k];
        const float4 wv = *reinterpret_cast<const float4*>(WL + k * FIN + c0);
        a0.x += a * wv.x; a0.y += a * wv.y; a0.z += a * wv.z; a0.w += a * wv.w;
    }
    *reinterpret_cast<float4*>(out + (size_t)n2 * FIN + c0) = a0;
}

extern "C" void kernel_launch(void* const* d_in, const int* in_sizes, int n_in,
                              void* d_out, int out_size, void* d_ws, size_t ws_size,
                              hipStream_t stream) {
    const float* x  = (const float*)d_in[0];
    const int*   ei = (const int*)d_in[1];
    const float* W1 = (const float*)d_in[2];
    const float* b1 = (const float*)d_in[3];
    const float* W2 = (const float*)d_in[4];
    const float* b2 = (const float*)d_in[5];
    float* out = (float*)d_out;

    char* w = (char*)d_ws;
    auto align = [](size_t v) { return (v + 255) & ~(size_t)255; };
    int*    phist = (int*)w;    w += align((size_t)NCH * NB * 4);  // chunk-major
    int*    btot  = (int*)w;    w += align((size_t)NB * 4);
    int*    bbase = (int*)w;    w += align((size_t)(NB + 1) * 4);
    int*    ebuf  = (int*)w;    w += align((size_t)NE * 4);        // packed src*128+(dst&127)
    int*    off   = (int*)w;    w += align((size_t)(NN + 1) * 4);
    float*  dis   = (float*)w;  w += align((size_t)NN * 4);
    int*    csr   = (int*)w;    w += align((size_t)NE * 4);
    __half* h1    = (__half*)w; w += align((size_t)NN * FHID * 2);
    __half* hbuf  = (__half*)w; w += align((size_t)NN * FHID * 2);

    const int* dst = ei + NE;
    k_bhist<<<NCH, 256, 0, stream>>>(dst, phist);
    k_bscan<<<NB, 256, 0, stream>>>(phist, btot);
    k_bbase<<<1, 1024, 0, stream>>>(btot, bbase, off);
    k_scatter_gemm1<<<NCH + GEMB, 256, 0, stream>>>(ei, phist, bbase, ebuf, x, W1, h1);
    k_csr<<<NB, 256, 0, stream>>>(ebuf, bbase, off, dis, csr);
    k_gather1<<<(NN * 16) / 256, 256, 0, stream>>>(off, csr, dis, h1, b1, hbuf);
    k_gather_mm<<<NN / 16, 256, 0, stream>>>(off, csr, dis, hbuf, W2, b2, out);
}